// Round 6
// baseline (257.044 us; speedup 1.0000x reference)
//
#include <hip/hip_runtime.h>
#include <hip/hip_bf16.h>
#include <cstdint>
#include <cstddef>

// Shapes (compile-time)
#define Bq 4
#define Nseq 1024
#define Dm 1024
#define Hh 16
#define HDd 64
#define FFd 2048
#define Mrows 4096  // B*N

typedef __attribute__((ext_vector_type(8))) short bf16x8;   // 8 bf16 = 4 VGPRs
typedef __attribute__((ext_vector_type(4))) float f32x4;
typedef __attribute__((ext_vector_type(16))) float f32x16;

__device__ __forceinline__ void gl_lds16(const void* g, void* l) {
  // async global->LDS, 16B per lane; LDS dest = wave-uniform base + lane*16
  __builtin_amdgcn_global_load_lds(
      (const __attribute__((address_space(1))) unsigned int*)g,
      (__attribute__((address_space(3))) unsigned int*)l, 16, 0, 0);
}

__device__ __forceinline__ unsigned short f2b(float f) {
  union { __hip_bfloat16 h; unsigned short u; } cv;
  cv.h = __float2bfloat16(f);
  return cv.u;
}

__device__ __forceinline__ unsigned cvt_pk_bf16(float a, float b) {
  unsigned r;
  asm("v_cvt_pk_bf16_f32 %0, %1, %2" : "=v"(r) : "v"(a), "v"(b));
  return r;  // low16 = bf16(a), high16 = bf16(b)
}

__device__ __forceinline__ void pl32_swap(unsigned& a, unsigned& b) {
  asm("v_permlane32_swap_b32 %0, %1" : "+v"(a), "+v"(b));
}

// ---------------- transpose + cast: src f32 [K][Ncols] -> dst bf16 [Ncols][K]
__global__ __launch_bounds__(256) void transpose_cast_k(
    const float* __restrict__ src, __hip_bfloat16* __restrict__ dst,
    int K, int Ncols) {
  __shared__ float tile[32][33];
  const int n0 = blockIdx.x * 32, k0 = blockIdx.y * 32;
  const int tx = threadIdx.x & 31, ty = threadIdx.x >> 5;  // ty 0..7
#pragma unroll
  for (int i = 0; i < 32; i += 8)
    tile[ty + i][tx] = src[(size_t)(k0 + ty + i) * Ncols + n0 + tx];
  __syncthreads();
#pragma unroll
  for (int i = 0; i < 32; i += 8)
    dst[(size_t)(n0 + ty + i) * K + k0 + tx] = __float2bfloat16(tile[tx][ty + i]);
}

// ---------------- layernorm: f32 [4096][1024] row -> bf16 out
__global__ __launch_bounds__(256) void ln_kernel(
    const float* __restrict__ x, const float* __restrict__ gw,
    const float* __restrict__ bw, __hip_bfloat16* __restrict__ out) {
  const int row = blockIdx.x;
  const float4 v = reinterpret_cast<const float4*>(x + (size_t)row * Dm)[threadIdx.x];
  float s1 = v.x + v.y + v.z + v.w;
  float s2 = v.x * v.x + v.y * v.y + v.z * v.z + v.w * v.w;
#pragma unroll
  for (int m = 1; m < 64; m <<= 1) {
    s1 += __shfl_xor(s1, m);
    s2 += __shfl_xor(s2, m);
  }
  __shared__ float a1[4], a2[4];
  const int wv = threadIdx.x >> 6;
  if ((threadIdx.x & 63) == 0) { a1[wv] = s1; a2[wv] = s2; }
  __syncthreads();
  s1 = a1[0] + a1[1] + a1[2] + a1[3];
  s2 = a2[0] + a2[1] + a2[2] + a2[3];
  const float mu = s1 * (1.f / Dm);
  const float rs = rsqrtf(s2 * (1.f / Dm) - mu * mu + 1e-5f);
  const float4 g4 = reinterpret_cast<const float4*>(gw)[threadIdx.x];
  const float4 b4 = reinterpret_cast<const float4*>(bw)[threadIdx.x];
  ushort4 o;
  o.x = f2b((v.x - mu) * rs * g4.x + b4.x);
  o.y = f2b((v.y - mu) * rs * g4.y + b4.y);
  o.z = f2b((v.z - mu) * rs * g4.z + b4.z);
  o.w = f2b((v.w - mu) * rs * g4.w + b4.w);
  reinterpret_cast<ushort4*>(out + (size_t)row * Dm)[threadIdx.x] = o;
}

// ---------------- GEMM (R4 structure): 128x128 tile, BK=32, 16x16x32 MFMA,
// single-buffer, 2 barriers/iter. Used for narrow-N GEMMs (outproj, FFN2).
// EPI 1: f32 out = acc + bias + res   (residual add)
template <int EPI>
__global__ __launch_bounds__(256, 2) void gemm_bt(
    const __hip_bfloat16* __restrict__ A, const __hip_bfloat16* __restrict__ BT,
    const float* __restrict__ bias, const float* __restrict__ res,
    float* __restrict__ outF, __hip_bfloat16* __restrict__ outB,
    int Ndim, int Kdim) {
  __shared__ alignas(16) __hip_bfloat16 As[128 * 32];
  __shared__ alignas(16) __hip_bfloat16 Bs[128 * 32];
  const int tid = threadIdx.x;
  const int wv = tid >> 6, ln = tid & 63;
  const int wr = wv >> 1, wc = wv & 1;
  const int rowBase = blockIdx.y * 128;
  const int colBase = blockIdx.x * 128;

  f32x4 acc[4][4];
#pragma unroll
  for (int i = 0; i < 4; ++i)
#pragma unroll
    for (int j = 0; j < 4; ++j) acc[i][j] = {0.f, 0.f, 0.f, 0.f};

  const int lr = ln >> 2;        // row within 16-row staging chunk
  const int lc = (ln & 3) * 8;   // k-element offset within row
  const int fr = ln & 15, kq = (ln >> 4) * 8;

  for (int k0 = 0; k0 < Kdim; k0 += 32) {
#pragma unroll
    for (int c = 0; c < 2; ++c) {
      const int chunk = c * 4 + wv;  // 0..7, 16 rows each
      gl_lds16(A + (size_t)(rowBase + chunk * 16 + lr) * Kdim + k0 + lc,
               (char*)As + chunk * 1024);
      gl_lds16(BT + (size_t)(colBase + chunk * 16 + lr) * Kdim + k0 + lc,
               (char*)Bs + chunk * 1024);
    }
    __syncthreads();
    bf16x8 af[4], bfr[4];
#pragma unroll
    for (int i = 0; i < 4; ++i)
      af[i] = *reinterpret_cast<const bf16x8*>(As + (wr * 64 + i * 16 + fr) * 32 + kq);
#pragma unroll
    for (int j = 0; j < 4; ++j)
      bfr[j] = *reinterpret_cast<const bf16x8*>(Bs + (wc * 64 + j * 16 + fr) * 32 + kq);
#pragma unroll
    for (int i = 0; i < 4; ++i)
#pragma unroll
      for (int j = 0; j < 4; ++j)
        acc[i][j] = __builtin_amdgcn_mfma_f32_16x16x32_bf16(af[i], bfr[j], acc[i][j], 0, 0, 0);
    __syncthreads();
  }

  const int rq = (ln >> 4) * 4;
#pragma unroll
  for (int i = 0; i < 4; ++i) {
#pragma unroll
    for (int j = 0; j < 4; ++j) {
      const int gc = colBase + wc * 64 + j * 16 + fr;
      const float bv = bias[gc];
#pragma unroll
      for (int ii = 0; ii < 4; ++ii) {
        const int gr = rowBase + wr * 64 + i * 16 + rq + ii;
        float v = acc[i][j][ii] + bv;
        if constexpr (EPI == 1) {
          outF[(size_t)gr * Ndim + gc] = v + res[(size_t)gr * Ndim + gc];
        } else {
          outB[(size_t)gr * Ndim + gc] =
              __float2bfloat16(0.5f * v * (1.f + erff(v * 0.70710678118f)));
        }
      }
    }
  }
}

// ---------------- GEMM v3 "gemm8": 256x128 tile, BK=64, 512 thr = 8 waves
// (4M x 2N, per-wave 64x64 via 2x2 mfma_32x32x16). TRIPLE-buffered LDS ring
// (slot(kt)=kt%3; tile kt+2 stages into a slot idle since iter kt-1), counted
// s_waitcnt vmcnt(6) -- never 0 in the loop -- raw s_barrier (no __syncthreads
// => no implicit vmcnt(0) drain). 4 phases/K-tile, 2 barriers + setprio/phase.
// Proof of the vmcnt count: per tile each wave issues 6 global_load_lds
// (A rounds 0-3 at phases 0-1, B rounds 0-1 at phase 2). At phase 3 the wave
// has <=12 outstanding (6 for tile kt+1 from last iter, 6 for kt+2 from this
// iter); vmcnt(6) retires the older 6 => tile kt+1 resident; the barrier after
// it publishes that to all waves before iter kt+1 reads.
// EPI 0: scatter q(+scale)/k/v^T bf16 ; EPI 2: bf16 gelu(acc+bias)
template <int EPI>
__global__ __launch_bounds__(512, 1) void gemm8(
    const __hip_bfloat16* __restrict__ A, const __hip_bfloat16* __restrict__ BT,
    const float* __restrict__ bias,
    __hip_bfloat16* __restrict__ outB,
    __hip_bfloat16* __restrict__ qb, __hip_bfloat16* __restrict__ kb,
    __hip_bfloat16* __restrict__ vtb, int Ndim, int Kdim) {
  __shared__ alignas(16) __hip_bfloat16 As[3][256 * 64];  // 3 x 32KB
  __shared__ alignas(16) __hip_bfloat16 Bs[3][128 * 64];  // 3 x 16KB
  const int tid = threadIdx.x;
  const int ln = tid & 63;
  const int w = tid >> 6;           // 0..7
  const int wm = w >> 1, wn = w & 1;
  const int lq = ln & 31, hl = ln >> 5;
  const int rowBase = blockIdx.y * 256;
  const int colBase = blockIdx.x * 128;
  // staging: row = 64 bf16 = 128B = 8 x 16B chunks; one issue-round = 512thr
  // x 16B = 8KB = 64 rows. Source chunk XOR-swizzled by row&7 (linear LDS dest).
  const int st_row = tid >> 3;                  // 0..63 within round
  const int st_c = (tid & 7) ^ (st_row & 7);    // swizzled 16B-chunk
  const int nt = Kdim >> 6;

  f32x16 acc[2][2];
#pragma unroll
  for (int i = 0; i < 2; ++i)
#pragma unroll
    for (int j = 0; j < 2; ++j) acc[i][j] = {};

  auto stageA = [&](int slot, int kt2, int r) {
    gl_lds16(A + (size_t)(rowBase + r * 64 + st_row) * Kdim + (kt2 << 6) + st_c * 8,
             (char*)&As[slot][0] + r * 8192 + tid * 16);
  };
  auto stageB = [&](int slot, int kt2, int r) {
    gl_lds16(BT + (size_t)(colBase + r * 64 + st_row) * Kdim + (kt2 << 6) + st_c * 8,
             (char*)&Bs[slot][0] + r * 8192 + tid * 16);
  };

  // prologue: tiles 0 and 1 fully issued; wait for tile 0 (leave tile 1's 6).
#pragma unroll
  for (int r = 0; r < 4; ++r) stageA(0, 0, r);
#pragma unroll
  for (int r = 0; r < 2; ++r) stageB(0, 0, r);
#pragma unroll
  for (int r = 0; r < 4; ++r) stageA(1, 1, r);
#pragma unroll
  for (int r = 0; r < 2; ++r) stageB(1, 1, r);
  asm volatile("s_waitcnt vmcnt(6)" ::: "memory");
  __builtin_amdgcn_s_barrier();

  for (int kt = 0; kt < nt; ++kt) {
    const int slot = kt % 3;
    const int nslot = (kt + 2) % 3;
    const bool pf = (kt + 2) < nt;
    const char* Ap = (const char*)&As[slot][0];
    const char* Bp = (const char*)&Bs[slot][0];
#pragma unroll
    for (int ks = 0; ks < 4; ++ks) {
      if (ks == 0 && pf) { stageA(nslot, kt + 2, 0); stageA(nslot, kt + 2, 1); }
      if (ks == 1 && pf) { stageA(nslot, kt + 2, 2); stageA(nslot, kt + 2, 3); }
      if (ks == 2 && pf) { stageB(nslot, kt + 2, 0); stageB(nslot, kt + 2, 1); }
      bf16x8 af[2], bfr[2];
#pragma unroll
      for (int i = 0; i < 2; ++i)
        af[i] = *reinterpret_cast<const bf16x8*>(
            Ap + (wm * 64 + i * 32 + lq) * 128 + (((ks * 2 + hl) ^ (lq & 7)) * 16));
#pragma unroll
      for (int j = 0; j < 2; ++j)
        bfr[j] = *reinterpret_cast<const bf16x8*>(
            Bp + (wn * 64 + j * 32 + lq) * 128 + (((ks * 2 + hl) ^ (lq & 7)) * 16));
      __builtin_amdgcn_s_barrier();  // align waves; compiler emits lgkm waits
      __builtin_amdgcn_s_setprio(1);
#pragma unroll
      for (int i = 0; i < 2; ++i)
#pragma unroll
        for (int j = 0; j < 2; ++j)
          acc[i][j] = __builtin_amdgcn_mfma_f32_32x32x16_bf16(af[i], bfr[j], acc[i][j], 0, 0, 0);
      __builtin_amdgcn_s_setprio(0);
      if (ks == 3) {
        if (pf) {
          asm volatile("s_waitcnt vmcnt(6)" ::: "memory");
        } else if (kt + 1 < nt) {
          asm volatile("s_waitcnt vmcnt(0)" ::: "memory");
        }
      }
      __builtin_amdgcn_s_barrier();
    }
  }

  // epilogue: 32x32 C/D layout: col = lq, row = (r&3) + 8*(r>>2) + 4*hl
#pragma unroll
  for (int i = 0; i < 2; ++i) {
#pragma unroll
    for (int j = 0; j < 2; ++j) {
      const int gc = colBase + wn * 64 + j * 32 + lq;
      const float bv = bias[gc];
#pragma unroll
      for (int r = 0; r < 16; ++r) {
        const int gr = rowBase + wm * 64 + i * 32 + (r & 3) + 8 * (r >> 2) + 4 * hl;
        float v = acc[i][j][r] + bv;
        if constexpr (EPI == 0) {
          const int which = gc >> 10;
          const int dcol = gc & 1023;
          const int h = dcol >> 6, hd = dcol & 63;
          const int b = gr >> 10, n = gr & 1023;
          const size_t bh = (size_t)(b * Hh + h);
          if (which == 0)
            qb[(bh * Nseq + n) * HDd + hd] = __float2bfloat16(v * 0.125f);
          else if (which == 1)
            kb[(bh * Nseq + n) * HDd + hd] = __float2bfloat16(v);
          else
            vtb[(bh * HDd + hd) * Nseq + n] = __float2bfloat16(v);
        } else {  // EPI == 2, exact GELU
          outB[(size_t)gr * Ndim + gc] =
              __float2bfloat16(0.5f * v * (1.f + erff(v * 0.70710678118f)));
        }
      }
    }
  }
}

// ---------------- flash attention v4 (unchanged from round 4/5; verified)
__global__ __launch_bounds__(256, 2) void attn_kernel(
    const __hip_bfloat16* __restrict__ q, const __hip_bfloat16* __restrict__ k,
    const __hip_bfloat16* __restrict__ vt, __hip_bfloat16* __restrict__ attn) {
  __shared__ alignas(16) __hip_bfloat16 Ks[2][64 * 64];  // [kv][d]
  __shared__ alignas(16) __hip_bfloat16 Vs[2][64 * 64];  // [d][kv]
  const int tid = threadIdx.x, wv = tid >> 6, ln = tid & 63;
  const int bh = blockIdx.x >> 3, qt = blockIdx.x & 7;
  const int b = bh >> 4, h = bh & 15;
  const int lq = ln & 31;
  const int hl = ln >> 5;

  const __hip_bfloat16* kbase = k + (size_t)bh * Nseq * HDd;
  const __hip_bfloat16* vbase = vt + (size_t)bh * HDd * Nseq;

  const int st_r = ln >> 3;
  const int st_c = (ln & 7) ^ st_r;

  const __hip_bfloat16* qsrc = q + ((size_t)bh * Nseq + qt * 128 + wv * 32 + lq) * HDd;
  bf16x8 qf[4];
#pragma unroll
  for (int s = 0; s < 4; ++s)
    qf[s] = *reinterpret_cast<const bf16x8*>(qsrc + s * 16 + hl * 8);

  float mrun = -1e30f, lrun = 0.f;
  f32x16 ot0 = {}, ot1 = {};

  auto stage = [&](int buf, int kt) {
#pragma unroll
    for (int c = 0; c < 2; ++c) {
      const int chunk = wv * 2 + c;
      gl_lds16(kbase + ((size_t)kt * 64 + chunk * 8 + st_r) * HDd + st_c * 8,
               (char*)&Ks[buf][0] + chunk * 1024);
      gl_lds16(vbase + (size_t)(chunk * 8 + st_r) * Nseq + kt * 64 + st_c * 8,
               (char*)&Vs[buf][0] + chunk * 1024);
    }
  };

  stage(0, 0);
  __syncthreads();
  int cur = 0;

  for (int kt = 0; kt < 16; ++kt) {
    if (kt < 15) stage(cur ^ 1, kt + 1);

    const char* Kp = (const char*)&Ks[cur][0];
    const char* Vp = (const char*)&Vs[cur][0];

    f32x16 st0 = {}, st1 = {};
#pragma unroll
    for (int t = 0; t < 2; ++t) {
      const int row = t * 32 + lq;
#pragma unroll
      for (int s = 0; s < 4; ++s) {
        const bf16x8 kf = *reinterpret_cast<const bf16x8*>(
            Kp + row * 128 + (((s * 2 + hl) ^ (row & 7)) * 16));
        if (t == 0) st0 = __builtin_amdgcn_mfma_f32_32x32x16_bf16(kf, qf[s], st0, 0, 0, 0);
        else        st1 = __builtin_amdgcn_mfma_f32_32x32x16_bf16(kf, qf[s], st1, 0, 0, 0);
      }
    }

    float tmax = st0[0];
#pragma unroll
    for (int r = 1; r < 16; ++r) tmax = fmaxf(tmax, st0[r]);
#pragma unroll
    for (int r = 0; r < 16; ++r) tmax = fmaxf(tmax, st1[r]);
    tmax = fmaxf(tmax, __shfl_xor(tmax, 32));
    const float mn = fmaxf(mrun, tmax);
    const float sc = __expf(mrun - mn);
    mrun = mn;
    float tsum = 0.f;
#pragma unroll
    for (int r = 0; r < 16; ++r) {
      st0[r] = __expf(st0[r] - mn);
      tsum += st0[r];
    }
#pragma unroll
    for (int r = 0; r < 16; ++r) {
      st1[r] = __expf(st1[r] - mn);
      tsum += st1[r];
    }
    tsum += __shfl_xor(tsum, 32);
    lrun = lrun * sc + tsum;
#pragma unroll
    for (int r = 0; r < 16; ++r) { ot0[r] *= sc; ot1[r] *= sc; }

    union PF { unsigned u[4]; bf16x8 v; } pf[4];
#pragma unroll
    for (int t = 0; t < 2; ++t)
#pragma unroll
      for (int g = 0; g < 2; ++g) {
        unsigned w0, w1, w2, w3;
        if (t == 0) {
          w0 = cvt_pk_bf16(st0[g * 8 + 0], st0[g * 8 + 1]);
          w1 = cvt_pk_bf16(st0[g * 8 + 2], st0[g * 8 + 3]);
          w2 = cvt_pk_bf16(st0[g * 8 + 4], st0[g * 8 + 5]);
          w3 = cvt_pk_bf16(st0[g * 8 + 6], st0[g * 8 + 7]);
        } else {
          w0 = cvt_pk_bf16(st1[g * 8 + 0], st1[g * 8 + 1]);
          w1 = cvt_pk_bf16(st1[g * 8 + 2], st1[g * 8 + 3]);
          w2 = cvt_pk_bf16(st1[g * 8 + 4], st1[g * 8 + 5]);
          w3 = cvt_pk_bf16(st1[g * 8 + 6], st1[g * 8 + 7]);
        }
        pl32_swap(w0, w2);
        pl32_swap(w1, w3);
        PF f;
        f.u[0] = w0; f.u[1] = w1; f.u[2] = w2; f.u[3] = w3;
        pf[t * 2 + g] = f;
      }

#pragma unroll
    for (int dt = 0; dt < 2; ++dt) {
      const int row = dt * 32 + lq;
#pragma unroll
      for (int ks = 0; ks < 4; ++ks) {
        const bf16x8 vf = *reinterpret_cast<const bf16x8*>(
            Vp + row * 128 + (((ks * 2 + hl) ^ (row & 7)) * 16));
        if (dt == 0) ot0 = __builtin_amdgcn_mfma_f32_32x32x16_bf16(vf, pf[ks].v, ot0, 0, 0, 0);
        else         ot1 = __builtin_amdgcn_mfma_f32_32x32x16_bf16(vf, pf[ks].v, ot1, 0, 0, 0);
      }
    }

    __syncthreads();
    cur ^= 1;
  }

  const float inv = 1.f / lrun;
  char* swb = (char*)(&Ks[0][0] + wv * 2048);
#pragma unroll
  for (int dt = 0; dt < 2; ++dt)
#pragma unroll
    for (int i = 0; i < 8; ++i) {
      const unsigned w = (dt == 0)
          ? cvt_pk_bf16(ot0[2 * i] * inv, ot0[2 * i + 1] * inv)
          : cvt_pk_bf16(ot1[2 * i] * inv, ot1[2 * i + 1] * inv);
      const int d0 = (2 * i & 2) + 8 * (i >> 1) + 4 * hl + 32 * dt;
      *(unsigned*)(swb + lq * 128 + (((d0 >> 3) ^ (lq & 7)) * 16) + (d0 & 7) * 2) = w;
    }
  const int brow = b * Nseq + qt * 128 + wv * 32;
#pragma unroll
  for (int it = 0; it < 4; ++it) {
    const int qr = it * 8 + (ln >> 3);
    const bf16x8 o = *reinterpret_cast<const bf16x8*>(
        swb + qr * 128 + (((ln & 7) ^ (qr & 7)) * 16));
    *reinterpret_cast<bf16x8*>(attn + (size_t)(brow + qr) * Dm + h * 64 + (ln & 7) * 8) = o;
  }
}

extern "C" void kernel_launch(void* const* d_in, const int* in_sizes, int n_in,
                              void* d_out, int out_size, void* d_ws, size_t ws_size,
                              hipStream_t stream) {
  (void)in_sizes; (void)n_in; (void)out_size; (void)ws_size;
  const float* x     = (const float*)d_in[0];
  const float* ln1_g = (const float*)d_in[1];
  const float* ln1_b = (const float*)d_in[2];
  const float* qkv_w = (const float*)d_in[3];
  const float* qkv_b = (const float*)d_in[4];
  const float* out_w = (const float*)d_in[5];
  const float* out_b = (const float*)d_in[6];
  const float* ln2_g = (const float*)d_in[7];
  const float* ln2_b = (const float*)d_in[8];
  const float* w1    = (const float*)d_in[9];
  const float* b1    = (const float*)d_in[10];
  const float* w2    = (const float*)d_in[11];
  const float* b2    = (const float*)d_in[12];
  float* outp = (float*)d_out;

  char* ws = (char*)d_ws;
  size_t off = 0;
  auto take = [&](size_t bytes) {
    char* p = ws + off;
    off += (bytes + 255) & ~(size_t)255;
    return p;
  };
  __hip_bfloat16* wqkv_t = (__hip_bfloat16*)take((size_t)3 * Dm * Dm * 2);
  __hip_bfloat16* wout_t = (__hip_bfloat16*)take((size_t)Dm * Dm * 2);
  __hip_bfloat16* w1_t   = (__hip_bfloat16*)take((size_t)FFd * Dm * 2);
  __hip_bfloat16* w2_t   = (__hip_bfloat16*)take((size_t)Dm * FFd * 2);
  __hip_bfloat16* xn     = (__hip_bfloat16*)take((size_t)Mrows * Dm * 2);  // reused as LN2 out
  __hip_bfloat16* qb     = (__hip_bfloat16*)take((size_t)Mrows * Dm * 2);
  __hip_bfloat16* kb     = (__hip_bfloat16*)take((size_t)Mrows * Dm * 2);
  __hip_bfloat16* vtb    = (__hip_bfloat16*)take((size_t)Mrows * Dm * 2);
  __hip_bfloat16* attn   = (__hip_bfloat16*)take((size_t)Mrows * Dm * 2);
  float*          x1     = (float*)take((size_t)Mrows * Dm * 4);
  __hip_bfloat16* gbuf   = (__hip_bfloat16*)take((size_t)Mrows * FFd * 2);

  const dim3 blk(256);
  // weight transposes (f32 [K][N] -> bf16 [N][K])
  transpose_cast_k<<<dim3(3 * Dm / 32, Dm / 32), blk, 0, stream>>>(qkv_w, wqkv_t, Dm, 3 * Dm);
  transpose_cast_k<<<dim3(Dm / 32, Dm / 32), blk, 0, stream>>>(out_w, wout_t, Dm, Dm);
  transpose_cast_k<<<dim3(FFd / 32, Dm / 32), blk, 0, stream>>>(w1, w1_t, Dm, FFd);
  transpose_cast_k<<<dim3(Dm / 32, FFd / 32), blk, 0, stream>>>(w2, w2_t, FFd, Dm);
  // LN1
  ln_kernel<<<dim3(Mrows), blk, 0, stream>>>(x, ln1_g, ln1_b, xn);
  // QKV projection (pipelined 256x128), scatter q/k/v^T
  gemm8<0><<<dim3(3 * Dm / 128, Mrows / 256), dim3(512), 0, stream>>>(
      xn, wqkv_t, qkv_b, nullptr, qb, kb, vtb, 3 * Dm, Dm);
  // attention (swapped 32x32 MFMA): 64 bh x 8 q-tiles of 128 rows
  attn_kernel<<<dim3(Bq * Hh * (Nseq / 128)), blk, 0, stream>>>(qb, kb, vtb, attn);
  // output projection + residual -> x1 (f32), R4 gemm (N=1024: full grid)
  gemm_bt<1><<<dim3(Dm / 128, Mrows / 128), blk, 0, stream>>>(
      attn, wout_t, out_b, x, x1, nullptr, Dm, Dm);
  // LN2
  ln_kernel<<<dim3(Mrows), blk, 0, stream>>>(x1, ln2_g, ln2_b, xn);
  // FFN1 + GELU (pipelined 256x128) -> gbuf (bf16)
  gemm8<2><<<dim3(FFd / 128, Mrows / 256), dim3(512), 0, stream>>>(
      xn, w1_t, b1, gbuf, nullptr, nullptr, nullptr, FFd, Dm);
  // FFN2 + residual -> out (f32), R4 gemm
  gemm_bt<1><<<dim3(Dm / 128, Mrows / 128), blk, 0, stream>>>(
      gbuf, w2_t, b2, x1, outp, nullptr, Dm, FFd);
}

// Round 7
// 191.679 us; speedup vs baseline: 1.3410x; 1.3410x over previous
//
#include <hip/hip_runtime.h>
#include <hip/hip_bf16.h>
#include <cstdint>
#include <cstddef>

// Shapes (compile-time)
#define Bq 4
#define Nseq 1024
#define Dm 1024
#define Hh 16
#define HDd 64
#define FFd 2048
#define Mrows 4096  // B*N

typedef __attribute__((ext_vector_type(8))) short bf16x8;   // 8 bf16 = 4 VGPRs
typedef __attribute__((ext_vector_type(4))) float f32x4;
typedef __attribute__((ext_vector_type(16))) float f32x16;

__device__ __forceinline__ void gl_lds16(const void* g, void* l) {
  // async global->LDS, 16B per lane; LDS dest = wave-uniform base + lane*16
  __builtin_amdgcn_global_load_lds(
      (const __attribute__((address_space(1))) unsigned int*)g,
      (__attribute__((address_space(3))) unsigned int*)l, 16, 0, 0);
}

__device__ __forceinline__ unsigned short f2b(float f) {
  union { __hip_bfloat16 h; unsigned short u; } cv;
  cv.h = __float2bfloat16(f);
  return cv.u;
}

__device__ __forceinline__ unsigned cvt_pk_bf16(float a, float b) {
  unsigned r;
  asm("v_cvt_pk_bf16_f32 %0, %1, %2" : "=v"(r) : "v"(a), "v"(b));
  return r;  // low16 = bf16(a), high16 = bf16(b)
}

__device__ __forceinline__ void pl32_swap(unsigned& a, unsigned& b) {
  asm("v_permlane32_swap_b32 %0, %1" : "+v"(a), "+v"(b));
}

// ---------------- transpose + cast: src f32 [K][Ncols] -> dst bf16 [Ncols][K]
__global__ __launch_bounds__(256) void transpose_cast_k(
    const float* __restrict__ src, __hip_bfloat16* __restrict__ dst,
    int K, int Ncols) {
  __shared__ float tile[32][33];
  const int n0 = blockIdx.x * 32, k0 = blockIdx.y * 32;
  const int tx = threadIdx.x & 31, ty = threadIdx.x >> 5;  // ty 0..7
#pragma unroll
  for (int i = 0; i < 32; i += 8)
    tile[ty + i][tx] = src[(size_t)(k0 + ty + i) * Ncols + n0 + tx];
  __syncthreads();
#pragma unroll
  for (int i = 0; i < 32; i += 8)
    dst[(size_t)(n0 + ty + i) * K + k0 + tx] = __float2bfloat16(tile[tx][ty + i]);
}

// ---------------- layernorm: f32 [4096][1024] row -> bf16 out
__global__ __launch_bounds__(256) void ln_kernel(
    const float* __restrict__ x, const float* __restrict__ gw,
    const float* __restrict__ bw, __hip_bfloat16* __restrict__ out) {
  const int row = blockIdx.x;
  const float4 v = reinterpret_cast<const float4*>(x + (size_t)row * Dm)[threadIdx.x];
  float s1 = v.x + v.y + v.z + v.w;
  float s2 = v.x * v.x + v.y * v.y + v.z * v.z + v.w * v.w;
#pragma unroll
  for (int m = 1; m < 64; m <<= 1) {
    s1 += __shfl_xor(s1, m);
    s2 += __shfl_xor(s2, m);
  }
  __shared__ float a1[4], a2[4];
  const int wv = threadIdx.x >> 6;
  if ((threadIdx.x & 63) == 0) { a1[wv] = s1; a2[wv] = s2; }
  __syncthreads();
  s1 = a1[0] + a1[1] + a1[2] + a1[3];
  s2 = a2[0] + a2[1] + a2[2] + a2[3];
  const float mu = s1 * (1.f / Dm);
  const float rs = rsqrtf(s2 * (1.f / Dm) - mu * mu + 1e-5f);
  const float4 g4 = reinterpret_cast<const float4*>(gw)[threadIdx.x];
  const float4 b4 = reinterpret_cast<const float4*>(bw)[threadIdx.x];
  ushort4 o;
  o.x = f2b((v.x - mu) * rs * g4.x + b4.x);
  o.y = f2b((v.y - mu) * rs * g4.y + b4.y);
  o.z = f2b((v.z - mu) * rs * g4.z + b4.z);
  o.w = f2b((v.w - mu) * rs * g4.w + b4.w);
  reinterpret_cast<ushort4*>(out + (size_t)row * Dm)[threadIdx.x] = o;
}

// ---------------- GEMM v4: 128x128 tile, BK=64, SINGLE-buffer (32 KB LDS ->
// ~4 blocks/CU), 32x32x16 MFMA, 2 __syncthreads per K-iter. Fragment layouts
// and XOR source-swizzle carried unchanged from the R5/R6-verified kernels.
// EPI 0: scatter q(+scale)/k/v^T bf16
// EPI 1: f32 out = acc + bias + res   (residual add)
// EPI 2: bf16 out = gelu(acc + bias)
template <int EPI>
__global__ __launch_bounds__(256, 3) void gemm_bt(
    const __hip_bfloat16* __restrict__ A, const __hip_bfloat16* __restrict__ BT,
    const float* __restrict__ bias, const float* __restrict__ res,
    float* __restrict__ outF, __hip_bfloat16* __restrict__ outB,
    __hip_bfloat16* __restrict__ qb, __hip_bfloat16* __restrict__ kb,
    __hip_bfloat16* __restrict__ vtb, int Ndim, int Kdim) {
  __shared__ alignas(16) __hip_bfloat16 As[128 * 64];  // 16 KB
  __shared__ alignas(16) __hip_bfloat16 Bs[128 * 64];  // 16 KB
  const int tid = threadIdx.x;
  const int wv = tid >> 6, ln = tid & 63;
  const int wm = wv >> 1, wn = wv & 1;
  const int lq = ln & 31, hl = ln >> 5;
  const int rowBase = blockIdx.y * 128;
  const int colBase = blockIdx.x * 128;

  // staging: tile row = 64 bf16 = 128B = 8 x 16B chunks; one round = 256 thr
  // x 16B = 4KB = 32 rows. Source chunk XOR-swizzled by row&7; LDS dest linear
  // (wave-uniform base, hw adds lane*16).
  const int st_row = tid >> 3;                 // 0..31 within round
  const int st_c = (tid & 7) ^ (st_row & 7);   // swizzled 16B-chunk index

  f32x16 acc[2][2];
#pragma unroll
  for (int i = 0; i < 2; ++i)
#pragma unroll
    for (int j = 0; j < 2; ++j) acc[i][j] = {};

  auto stage = [&](int k0) {
#pragma unroll
    for (int r = 0; r < 4; ++r) {
      gl_lds16(A + (size_t)(rowBase + r * 32 + st_row) * Kdim + k0 + st_c * 8,
               (char*)As + r * 4096 + wv * 1024);
      gl_lds16(BT + (size_t)(colBase + r * 32 + st_row) * Kdim + k0 + st_c * 8,
               (char*)Bs + r * 4096 + wv * 1024);
    }
  };

  const int nt = Kdim >> 6;
  for (int kt = 0; kt < nt; ++kt) {
    stage(kt << 6);
    __syncthreads();  // drains staging vmcnt, publishes tile
    const char* Ap = (const char*)As;
    const char* Bp = (const char*)Bs;
#pragma unroll
    for (int ks = 0; ks < 4; ++ks) {
      bf16x8 af[2], bfr[2];
#pragma unroll
      for (int i = 0; i < 2; ++i)
        af[i] = *reinterpret_cast<const bf16x8*>(
            Ap + (wm * 64 + i * 32 + lq) * 128 + (((ks * 2 + hl) ^ (lq & 7)) * 16));
#pragma unroll
      for (int j = 0; j < 2; ++j)
        bfr[j] = *reinterpret_cast<const bf16x8*>(
            Bp + (wn * 64 + j * 32 + lq) * 128 + (((ks * 2 + hl) ^ (lq & 7)) * 16));
#pragma unroll
      for (int i = 0; i < 2; ++i)
#pragma unroll
        for (int j = 0; j < 2; ++j)
          acc[i][j] = __builtin_amdgcn_mfma_f32_32x32x16_bf16(af[i], bfr[j], acc[i][j], 0, 0, 0);
    }
    __syncthreads();  // all reads done before next stage overwrites
  }

  // epilogue: 32x32 C/D layout: col = lq, row = (r&3) + 8*(r>>2) + 4*hl
#pragma unroll
  for (int i = 0; i < 2; ++i) {
#pragma unroll
    for (int j = 0; j < 2; ++j) {
      const int gc = colBase + wn * 64 + j * 32 + lq;
      const float bv = bias[gc];
#pragma unroll
      for (int r = 0; r < 16; ++r) {
        const int gr = rowBase + wm * 64 + i * 32 + (r & 3) + 8 * (r >> 2) + 4 * hl;
        float v = acc[i][j][r] + bv;
        if constexpr (EPI == 0) {
          const int which = gc >> 10;
          const int dcol = gc & 1023;
          const int h = dcol >> 6, hd = dcol & 63;
          const int b = gr >> 10, n = gr & 1023;
          const size_t bh = (size_t)(b * Hh + h);
          if (which == 0)
            qb[(bh * Nseq + n) * HDd + hd] = __float2bfloat16(v * 0.125f);
          else if (which == 1)
            kb[(bh * Nseq + n) * HDd + hd] = __float2bfloat16(v);
          else
            vtb[(bh * HDd + hd) * Nseq + n] = __float2bfloat16(v);
        } else if constexpr (EPI == 1) {
          outF[(size_t)gr * Ndim + gc] = v + res[(size_t)gr * Ndim + gc];
        } else {  // EPI == 2, exact GELU
          outB[(size_t)gr * Ndim + gc] =
              __float2bfloat16(0.5f * v * (1.f + erff(v * 0.70710678118f)));
        }
      }
    }
  }
}

// ---------------- flash attention v4 (unchanged; verified since round 4)
__global__ __launch_bounds__(256, 2) void attn_kernel(
    const __hip_bfloat16* __restrict__ q, const __hip_bfloat16* __restrict__ k,
    const __hip_bfloat16* __restrict__ vt, __hip_bfloat16* __restrict__ attn) {
  __shared__ alignas(16) __hip_bfloat16 Ks[2][64 * 64];  // [kv][d]
  __shared__ alignas(16) __hip_bfloat16 Vs[2][64 * 64];  // [d][kv]
  const int tid = threadIdx.x, wv = tid >> 6, ln = tid & 63;
  const int bh = blockIdx.x >> 3, qt = blockIdx.x & 7;
  const int b = bh >> 4, h = bh & 15;
  const int lq = ln & 31;
  const int hl = ln >> 5;

  const __hip_bfloat16* kbase = k + (size_t)bh * Nseq * HDd;
  const __hip_bfloat16* vbase = vt + (size_t)bh * HDd * Nseq;

  const int st_r = ln >> 3;
  const int st_c = (ln & 7) ^ st_r;

  const __hip_bfloat16* qsrc = q + ((size_t)bh * Nseq + qt * 128 + wv * 32 + lq) * HDd;
  bf16x8 qf[4];
#pragma unroll
  for (int s = 0; s < 4; ++s)
    qf[s] = *reinterpret_cast<const bf16x8*>(qsrc + s * 16 + hl * 8);

  float mrun = -1e30f, lrun = 0.f;
  f32x16 ot0 = {}, ot1 = {};

  auto stage = [&](int buf, int kt) {
#pragma unroll
    for (int c = 0; c < 2; ++c) {
      const int chunk = wv * 2 + c;
      gl_lds16(kbase + ((size_t)kt * 64 + chunk * 8 + st_r) * HDd + st_c * 8,
               (char*)&Ks[buf][0] + chunk * 1024);
      gl_lds16(vbase + (size_t)(chunk * 8 + st_r) * Nseq + kt * 64 + st_c * 8,
               (char*)&Vs[buf][0] + chunk * 1024);
    }
  };

  stage(0, 0);
  __syncthreads();
  int cur = 0;

  for (int kt = 0; kt < 16; ++kt) {
    if (kt < 15) stage(cur ^ 1, kt + 1);

    const char* Kp = (const char*)&Ks[cur][0];
    const char* Vp = (const char*)&Vs[cur][0];

    f32x16 st0 = {}, st1 = {};
#pragma unroll
    for (int t = 0; t < 2; ++t) {
      const int row = t * 32 + lq;
#pragma unroll
      for (int s = 0; s < 4; ++s) {
        const bf16x8 kf = *reinterpret_cast<const bf16x8*>(
            Kp + row * 128 + (((s * 2 + hl) ^ (row & 7)) * 16));
        if (t == 0) st0 = __builtin_amdgcn_mfma_f32_32x32x16_bf16(kf, qf[s], st0, 0, 0, 0);
        else        st1 = __builtin_amdgcn_mfma_f32_32x32x16_bf16(kf, qf[s], st1, 0, 0, 0);
      }
    }

    float tmax = st0[0];
#pragma unroll
    for (int r = 1; r < 16; ++r) tmax = fmaxf(tmax, st0[r]);
#pragma unroll
    for (int r = 0; r < 16; ++r) tmax = fmaxf(tmax, st1[r]);
    tmax = fmaxf(tmax, __shfl_xor(tmax, 32));
    const float mn = fmaxf(mrun, tmax);
    const float sc = __expf(mrun - mn);
    mrun = mn;
    float tsum = 0.f;
#pragma unroll
    for (int r = 0; r < 16; ++r) {
      st0[r] = __expf(st0[r] - mn);
      tsum += st0[r];
    }
#pragma unroll
    for (int r = 0; r < 16; ++r) {
      st1[r] = __expf(st1[r] - mn);
      tsum += st1[r];
    }
    tsum += __shfl_xor(tsum, 32);
    lrun = lrun * sc + tsum;
#pragma unroll
    for (int r = 0; r < 16; ++r) { ot0[r] *= sc; ot1[r] *= sc; }

    union PF { unsigned u[4]; bf16x8 v; } pf[4];
#pragma unroll
    for (int t = 0; t < 2; ++t)
#pragma unroll
      for (int g = 0; g < 2; ++g) {
        unsigned w0, w1, w2, w3;
        if (t == 0) {
          w0 = cvt_pk_bf16(st0[g * 8 + 0], st0[g * 8 + 1]);
          w1 = cvt_pk_bf16(st0[g * 8 + 2], st0[g * 8 + 3]);
          w2 = cvt_pk_bf16(st0[g * 8 + 4], st0[g * 8 + 5]);
          w3 = cvt_pk_bf16(st0[g * 8 + 6], st0[g * 8 + 7]);
        } else {
          w0 = cvt_pk_bf16(st1[g * 8 + 0], st1[g * 8 + 1]);
          w1 = cvt_pk_bf16(st1[g * 8 + 2], st1[g * 8 + 3]);
          w2 = cvt_pk_bf16(st1[g * 8 + 4], st1[g * 8 + 5]);
          w3 = cvt_pk_bf16(st1[g * 8 + 6], st1[g * 8 + 7]);
        }
        pl32_swap(w0, w2);
        pl32_swap(w1, w3);
        PF f;
        f.u[0] = w0; f.u[1] = w1; f.u[2] = w2; f.u[3] = w3;
        pf[t * 2 + g] = f;
      }

#pragma unroll
    for (int dt = 0; dt < 2; ++dt) {
      const int row = dt * 32 + lq;
#pragma unroll
      for (int ks = 0; ks < 4; ++ks) {
        const bf16x8 vf = *reinterpret_cast<const bf16x8*>(
            Vp + row * 128 + (((ks * 2 + hl) ^ (row & 7)) * 16));
        if (dt == 0) ot0 = __builtin_amdgcn_mfma_f32_32x32x16_bf16(vf, pf[ks].v, ot0, 0, 0, 0);
        else         ot1 = __builtin_amdgcn_mfma_f32_32x32x16_bf16(vf, pf[ks].v, ot1, 0, 0, 0);
      }
    }

    __syncthreads();
    cur ^= 1;
  }

  const float inv = 1.f / lrun;
  char* swb = (char*)(&Ks[0][0] + wv * 2048);
#pragma unroll
  for (int dt = 0; dt < 2; ++dt)
#pragma unroll
    for (int i = 0; i < 8; ++i) {
      const unsigned w = (dt == 0)
          ? cvt_pk_bf16(ot0[2 * i] * inv, ot0[2 * i + 1] * inv)
          : cvt_pk_bf16(ot1[2 * i] * inv, ot1[2 * i + 1] * inv);
      const int d0 = (2 * i & 2) + 8 * (i >> 1) + 4 * hl + 32 * dt;
      *(unsigned*)(swb + lq * 128 + (((d0 >> 3) ^ (lq & 7)) * 16) + (d0 & 7) * 2) = w;
    }
  const int brow = b * Nseq + qt * 128 + wv * 32;
#pragma unroll
  for (int it = 0; it < 4; ++it) {
    const int qr = it * 8 + (ln >> 3);
    const bf16x8 o = *reinterpret_cast<const bf16x8*>(
        swb + qr * 128 + (((ln & 7) ^ (qr & 7)) * 16));
    *reinterpret_cast<bf16x8*>(attn + (size_t)(brow + qr) * Dm + h * 64 + (ln & 7) * 8) = o;
  }
}

extern "C" void kernel_launch(void* const* d_in, const int* in_sizes, int n_in,
                              void* d_out, int out_size, void* d_ws, size_t ws_size,
                              hipStream_t stream) {
  (void)in_sizes; (void)n_in; (void)out_size; (void)ws_size;
  const float* x     = (const float*)d_in[0];
  const float* ln1_g = (const float*)d_in[1];
  const float* ln1_b = (const float*)d_in[2];
  const float* qkv_w = (const float*)d_in[3];
  const float* qkv_b = (const float*)d_in[4];
  const float* out_w = (const float*)d_in[5];
  const float* out_b = (const float*)d_in[6];
  const float* ln2_g = (const float*)d_in[7];
  const float* ln2_b = (const float*)d_in[8];
  const float* w1    = (const float*)d_in[9];
  const float* b1    = (const float*)d_in[10];
  const float* w2    = (const float*)d_in[11];
  const float* b2    = (const float*)d_in[12];
  float* outp = (float*)d_out;

  char* ws = (char*)d_ws;
  size_t off = 0;
  auto take = [&](size_t bytes) {
    char* p = ws + off;
    off += (bytes + 255) & ~(size_t)255;
    return p;
  };
  __hip_bfloat16* wqkv_t = (__hip_bfloat16*)take((size_t)3 * Dm * Dm * 2);
  __hip_bfloat16* wout_t = (__hip_bfloat16*)take((size_t)Dm * Dm * 2);
  __hip_bfloat16* w1_t   = (__hip_bfloat16*)take((size_t)FFd * Dm * 2);
  __hip_bfloat16* w2_t   = (__hip_bfloat16*)take((size_t)Dm * FFd * 2);
  __hip_bfloat16* xn     = (__hip_bfloat16*)take((size_t)Mrows * Dm * 2);  // reused as LN2 out
  __hip_bfloat16* qb     = (__hip_bfloat16*)take((size_t)Mrows * Dm * 2);
  __hip_bfloat16* kb     = (__hip_bfloat16*)take((size_t)Mrows * Dm * 2);
  __hip_bfloat16* vtb    = (__hip_bfloat16*)take((size_t)Mrows * Dm * 2);
  __hip_bfloat16* attn   = (__hip_bfloat16*)take((size_t)Mrows * Dm * 2);
  float*          x1     = (float*)take((size_t)Mrows * Dm * 4);
  __hip_bfloat16* gbuf   = (__hip_bfloat16*)take((size_t)Mrows * FFd * 2);

  const dim3 blk(256);
  // weight transposes (f32 [K][N] -> bf16 [N][K])
  transpose_cast_k<<<dim3(3 * Dm / 32, Dm / 32), blk, 0, stream>>>(qkv_w, wqkv_t, Dm, 3 * Dm);
  transpose_cast_k<<<dim3(Dm / 32, Dm / 32), blk, 0, stream>>>(out_w, wout_t, Dm, Dm);
  transpose_cast_k<<<dim3(FFd / 32, Dm / 32), blk, 0, stream>>>(w1, w1_t, Dm, FFd);
  transpose_cast_k<<<dim3(Dm / 32, FFd / 32), blk, 0, stream>>>(w2, w2_t, FFd, Dm);
  // LN1
  ln_kernel<<<dim3(Mrows), blk, 0, stream>>>(x, ln1_g, ln1_b, xn);
  // QKV projection, scatter q/k/v^T
  gemm_bt<0><<<dim3(3 * Dm / 128, Mrows / 128), blk, 0, stream>>>(
      xn, wqkv_t, qkv_b, nullptr, nullptr, nullptr, qb, kb, vtb, 3 * Dm, Dm);
  // attention (swapped 32x32 MFMA): 64 bh x 8 q-tiles of 128 rows
  attn_kernel<<<dim3(Bq * Hh * (Nseq / 128)), blk, 0, stream>>>(qb, kb, vtb, attn);
  // output projection + residual -> x1 (f32)
  gemm_bt<1><<<dim3(Dm / 128, Mrows / 128), blk, 0, stream>>>(
      attn, wout_t, out_b, x, x1, nullptr, nullptr, nullptr, nullptr, Dm, Dm);
  // LN2
  ln_kernel<<<dim3(Mrows), blk, 0, stream>>>(x1, ln2_g, ln2_b, xn);
  // FFN1 + GELU -> gbuf (bf16)
  gemm_bt<2><<<dim3(FFd / 128, Mrows / 128), blk, 0, stream>>>(
      xn, w1_t, b1, nullptr, nullptr, gbuf, nullptr, nullptr, nullptr, FFd, Dm);
  // FFN2 + residual -> out (f32)
  gemm_bt<1><<<dim3(Dm / 128, Mrows / 128), blk, 0, stream>>>(
      gbuf, w2_t, b2, x1, outp, nullptr, nullptr, nullptr, nullptr, Dm, FFd);
}